// Round 7
// baseline (603.832 us; speedup 1.0000x reference)
//
#include <hip/hip_runtime.h>

// VQ argmin: 1-pass f16 screen on matrix cores + exact fp32 parallel rescan
// for tokens with screen gap < MARGIN. R7: occupancy push — As/Bs LDS overlay
// (32 KB/block) + K-split over 2 chunks (grid 1024 = 4 blocks/CU) with
// R2-verified partial merge. K-loop/fold/rescan identical to verified R6.

#define M_TOK  32768
#define DIM    128
#define KCODES 8192
#define BM     64
#define NCHUNK 2
#define CHUNK  (KCODES / NCHUNK)   // 4096
#define NT     (CHUNK / 256)       // 16 n-tiles per block
#define MARGIN 0.10f               // ~8 sigma of screen pair error

typedef _Float16 half8v __attribute__((ext_vector_type(8)));
typedef float float4v __attribute__((ext_vector_type(4)));

union H2U { _Float16 h; unsigned short u; };
__device__ __forceinline__ unsigned short f2h_bits(_Float16 h) {
  H2U c; c.h = h; return c.u;
}

__device__ __forceinline__ void gload_lds16(const void* g, void* l) {
  __builtin_amdgcn_global_load_lds(
      (const __attribute__((address_space(1))) unsigned int*)g,
      (__attribute__((address_space(3))) unsigned int*)l, 16, 0, 0);
}

// ws: Cs f16[K][128] | cnorm f32[K] | qcnt | qtok | kmin | partials
#define CNORM_OFF  (KCODES * 256)
#define QCNT_OFF   (CNORM_OFF + KCODES * 4)
#define QTOK_OFF   (QCNT_OFF + 64)
#define KMIN_OFF   (QTOK_OFF + M_TOK * 4)
#define PART_OFF   (KMIN_OFF + M_TOK * 8)

// -------------------------------------------------------------------------
// prep: exact fp32 cnorm + f16-hi codebook rows. Zeroes qcnt.
__global__ __launch_bounds__(256) void prep_kernel(
    const float* __restrict__ cb, unsigned short* __restrict__ Cs,
    float* __restrict__ cnorm, int* __restrict__ qcnt) {
  if (blockIdx.x == 0 && threadIdx.x == 0) *qcnt = 0;
  const int k = blockIdx.x * 4 + (threadIdx.x >> 6);
  const int lane = threadIdx.x & 63;
  const float2 v = ((const float2*)(cb + (size_t)k * DIM))[lane];
  float s = v.x * v.x + v.y * v.y;
  #pragma unroll
  for (int off = 32; off > 0; off >>= 1) s += __shfl_down(s, off);
  if (lane == 0) cnorm[k] = s;
  ushort2 hi;
  hi.x = f2h_bits((_Float16)v.x);
  hi.y = f2h_bits((_Float16)v.y);
  *(ushort2*)(Cs + (size_t)k * 128 + lane * 2) = hi;
}

// -------------------------------------------------------------------------
// Screen kernel: block (bx, chunk) = 64 tokens x 4096 codes. LDS overlay:
// [0,16K) stages As (consumed into registers), then [0,32K) is Bs.
__global__ __launch_bounds__(256, 4) void vq_mfma_kernel(
    const float* __restrict__ ze, const unsigned short* __restrict__ Cs,
    const float* __restrict__ cnorm, float4* __restrict__ partials) {
  __shared__ char lds[32768];

  const int tid = threadIdx.x;
  const int wn = tid >> 6;
  const int lane = tid & 63;
  const int quad = lane >> 4;
  const int l15 = lane & 15;
  const int m0 = blockIdx.x * BM;
  const int cbase = blockIdx.y * CHUNK;

  // Per-lane B-staging source offsets (R2/R4/R6-verified mapping).
  int loffC[4];
  #pragma unroll
  for (int c = 0; c < 4; ++c) {
    const int r = c * 16 + (lane >> 2);
    const int s = lane & 3;
    const int seg = s ^ ((r >> 1) & 3);
    loffC[c] = (wn * 64 + r) * 256 + seg * 16;
  }
  int boff[4];
  #pragma unroll
  for (int j = 0; j < 4; ++j) {
    const int n = j * 16 + l15;
    boff[j] = n * 64 + ((quad ^ ((n >> 1) & 3)) << 4);
  }
  char* const BsW = lds + wn * 8192;  // 2 slice bufs x 4 KB per wave

  // ---- stage As (hi only) into lds[0,16K): seg = (c>>3) ^ (r&7) ----
  {
    char* const As = lds;
    const int r = tid >> 2;
    const int qh = tid & 3;
    const float* zrow = ze + (size_t)(m0 + r) * DIM + qh * 32;
    char* arow = As + r * 256;
    const int rx = r & 7;
    #pragma unroll
    for (int i = 0; i < 8; ++i) {
      const float4 v = *(const float4*)(zrow + i * 4);
      ushort4 hh;
      hh.x = f2h_bits((_Float16)v.x);
      hh.y = f2h_bits((_Float16)v.y);
      hh.z = f2h_bits((_Float16)v.z);
      hh.w = f2h_bits((_Float16)v.w);
      const int c = qh * 32 + i * 4;
      *(ushort4*)(arow + ((((c >> 3) ^ rx) << 4) | ((c & 7) << 1))) = hh;
    }
  }
  __syncthreads();

  // Preload A fragments into registers (64 VGPRs, reused for all n-tiles).
  half8v ahi[4][4];
  #pragma unroll
  for (int ks = 0; ks < 4; ++ks)
    #pragma unroll
    for (int i = 0; i < 4; ++i) {
      const int m = i * 16 + l15;
      const int kslot = ks * 4 + quad;
      ahi[ks][i] = *(const half8v*)(lds + m * 256 + ((kslot ^ (m & 7)) << 4));
    }
  __syncthreads();  // As region now free -> Bs owns [0,32K)

  float bestv[16], secv[16], idxv[16];
  #pragma unroll
  for (int s = 0; s < 16; ++s) {
    bestv[s] = 3.4e38f; secv[s] = 3.4e38f; idxv[s] = 0.f;
  }

  for (int nt = 0; nt < NT; ++nt) {
    const char* const tile = (const char*)Cs + (size_t)(cbase + nt * 256) * 256;
    float cnv[4];
    #pragma unroll
    for (int j = 0; j < 4; ++j)
      cnv[j] = cnorm[cbase + nt * 256 + wn * 64 + j * 16 + l15];

    float4v acc[4][4];
    #pragma unroll
    for (int i = 0; i < 4; ++i)
      #pragma unroll
      for (int j = 0; j < 4; ++j) acc[i][j] = (float4v)0.0f;

    // 4 k-slices per tile, staged two per barrier pair.
    #pragma unroll
    for (int t = 0; t < 2; ++t) {
      __syncthreads();
      #pragma unroll
      for (int p = 0; p < 2; ++p)
        #pragma unroll
        for (int c = 0; c < 4; ++c)
          gload_lds16(tile + (t * 2 + p) * 64 + loffC[c],
                      BsW + p * 4096 + c * 1024);
      __syncthreads();

      #pragma unroll
      for (int p = 0; p < 2; ++p) {
        const int kk = t * 2 + p;
        half8v bf[4];
        #pragma unroll
        for (int j = 0; j < 4; ++j)
          bf[j] = *(const half8v*)(BsW + p * 4096 + boff[j]);
        #pragma unroll
        for (int i = 0; i < 4; ++i)
          #pragma unroll
          for (int j = 0; j < 4; ++j)
            acc[i][j] = __builtin_amdgcn_mfma_f32_16x16x32_f16(
                ahi[kk][i], bf[j], acc[i][j], 0, 0, 0);
      }
    }

    // Fold screen scores. Ascending n, strict < -> lowest index on ties.
    #pragma unroll
    for (int j = 0; j < 4; ++j) {
      const float nidx = (float)(cbase + nt * 256 + wn * 64 + j * 16 + l15);
      const float cn = cnv[j];
      #pragma unroll
      for (int i = 0; i < 4; ++i)
        #pragma unroll
        for (int rg = 0; rg < 4; ++rg) {
          const float sc = fmaf(-2.0f, acc[i][j][rg], cn);
          const int slot = i * 4 + rg;
          const bool bt = sc < bestv[slot];
          secv[slot] = bt ? bestv[slot] : fminf(secv[slot], sc);
          idxv[slot] = bt ? nidx : idxv[slot];
          bestv[slot] = bt ? sc : bestv[slot];
        }
    }
  }

  // Cross-lane reduce (16 lanes per token row, tie -> lowest index).
  #pragma unroll
  for (int slot = 0; slot < 16; ++slot) {
    float b = bestv[slot], sec = secv[slot], ix = idxv[slot];
    #pragma unroll
    for (int mk = 1; mk <= 8; mk <<= 1) {
      const float ob = __shfl_xor(b, mk);
      const float os = __shfl_xor(sec, mk);
      const float oi = __shfl_xor(ix, mk);
      const bool take = (ob < b) || (ob == b && oi < ix);
      const float loser = take ? b : ob;
      b = take ? ob : b;
      ix = take ? oi : ix;
      sec = fminf(fminf(sec, os), loser);
    }
    bestv[slot] = b; secv[slot] = sec; idxv[slot] = ix;
  }

  // Cross-wave merge via LDS (Bs region reused after barrier).
  __syncthreads();
  float* const redB = (float*)lds;
  float* const redS = redB + 256;
  float* const redI = redB + 512;
  if (l15 == 0) {
    #pragma unroll
    for (int slot = 0; slot < 16; ++slot) {
      const int row = (slot >> 2) * 16 + quad * 4 + (slot & 3);
      redB[wn * 64 + row] = bestv[slot];
      redS[wn * 64 + row] = secv[slot];
      redI[wn * 64 + row] = idxv[slot];
    }
  }
  __syncthreads();
  if (tid < 64) {
    float b = redB[tid], sec = redS[tid], ix = redI[tid];
    #pragma unroll
    for (int w = 1; w < 4; ++w) {
      const float ob = redB[w * 64 + tid];
      const float os = redS[w * 64 + tid];
      const float oi = redI[w * 64 + tid];
      const bool take = (ob < b) || (ob == b && oi < ix);
      const float loser = take ? b : ob;
      b = take ? ob : b;
      ix = take ? oi : ix;
      sec = fminf(fminf(sec, os), loser);
    }
    partials[(size_t)blockIdx.y * M_TOK + m0 + tid] =
        make_float4(b, sec, ix, 0.f);
  }
}

// -------------------------------------------------------------------------
// Merge chunk partials (R2-verified identity), write idx, flag ambiguous
// tokens into the rescan queue, provisional z_q gather.
__global__ __launch_bounds__(256) void merge_kernel(
    const float* __restrict__ cb, const float4* __restrict__ partials,
    int* __restrict__ qcnt, int* __restrict__ qtok,
    unsigned long long* __restrict__ kmin,
    float* __restrict__ out_zq, float* __restrict__ out_idx) {
  __shared__ float lidxs[64];
  const int tid = threadIdx.x;
  const int t0 = blockIdx.x * 64;
  if (tid < 64) {
    const int token = t0 + tid;
    float4 p = partials[token];
    float b = p.x, sec = p.y, ix = p.z;
    #pragma unroll
    for (int c = 1; c < NCHUNK; ++c) {
      const float4 q = partials[(size_t)c * M_TOK + token];
      const bool take = (q.x < b) || (q.x == b && q.z < ix);
      const float loser = take ? b : q.x;
      b = take ? q.x : b;
      ix = take ? q.z : ix;
      sec = fminf(fminf(sec, q.y), loser);
    }
    out_idx[token] = ix;
    lidxs[tid] = ix;
    if (sec - b < MARGIN) {  // ambiguous under screen error -> exact rescan
      kmin[token] = ~0ull;
      const int p2 = atomicAdd(qcnt, 1);
      qtok[p2] = token;
    }
  }
  __syncthreads();
  const int tl = tid >> 2, qp = tid & 3;
  const int code = (int)lidxs[tl];
  const float4* src = (const float4*)(cb + (size_t)code * DIM);
  float4* dst = (float4*)(out_zq + (size_t)(t0 + tl) * DIM);
  #pragma unroll
  for (int p = 0; p < 8; ++p) dst[qp + p * 4] = src[qp + p * 4];
}

// -------------------------------------------------------------------------
// Parallel exact rescan (verified R5/R6): block b = (token slot b>>5,
// code chunk b&31); 256 threads score one code each; atomicMin merge.
__global__ __launch_bounds__(256) void rescan_part_kernel(
    const float* __restrict__ ze, const float* __restrict__ cb,
    const float* __restrict__ cnorm, const int* __restrict__ qcnt,
    const int* __restrict__ qtok, unsigned long long* __restrict__ kmin) {
  __shared__ float xsh[DIM];
  __shared__ float rs[256];
  __shared__ int ri[256];
  const int tid = threadIdx.x;
  const int chunk = blockIdx.x & 31;
  const int n = *qcnt;
  for (int qi = blockIdx.x >> 5; qi < n; qi += (gridDim.x >> 5)) {
    const int token = qtok[qi];
    __syncthreads();
    if (tid < 32)
      ((float4*)xsh)[tid] = ((const float4*)(ze + (size_t)token * DIM))[tid];
    __syncthreads();
    const int code = chunk * 256 + tid;
    const float* crow = cb + (size_t)code * DIM;
    float dot = 0.f;
    #pragma unroll
    for (int d = 0; d < DIM; ++d) dot = fmaf(xsh[d], crow[d], dot);
    rs[tid] = fmaf(-2.f, dot, cnorm[code]);
    ri[tid] = code;
    __syncthreads();
    #pragma unroll
    for (int off = 128; off > 0; off >>= 1) {
      if (tid < off) {
        const float so = rs[tid + off];
        const int io = ri[tid + off];
        if (so < rs[tid] || (so == rs[tid] && io < ri[tid])) {
          rs[tid] = so; ri[tid] = io;
        }
      }
      __syncthreads();
    }
    if (tid == 0) {
      union { float f; unsigned int u; } c; c.f = rs[0];
      const unsigned int m = (c.u >> 31) ? ~c.u : (c.u | 0x80000000u);
      const unsigned long long key =
          ((unsigned long long)m << 32) | (unsigned int)ri[0];
      atomicMin(&kmin[token], key);
    }
    __syncthreads();
  }
}

// -------------------------------------------------------------------------
// Apply rescan results: decode keys, rewrite idx + z_q rows.
__global__ __launch_bounds__(256) void rescan_apply_kernel(
    const float* __restrict__ cb, const int* __restrict__ qcnt,
    const int* __restrict__ qtok, const unsigned long long* __restrict__ kmin,
    float* __restrict__ out_zq, float* __restrict__ out_idx) {
  const int tid = threadIdx.x;
  const int n = *qcnt;
  for (int qi = blockIdx.x; qi < n; qi += gridDim.x) {
    const int token = qtok[qi];
    const int code = (int)(unsigned int)(kmin[token] & 0xFFFFFFFFull);
    if (tid == 0) out_idx[token] = (float)code;
    if (tid < 32)
      ((float4*)(out_zq + (size_t)token * DIM))[tid] =
          ((const float4*)(cb + (size_t)code * DIM))[tid];
  }
}

// -------------------------------------------------------------------------
extern "C" void kernel_launch(void* const* d_in, const int* in_sizes, int n_in,
                              void* d_out, int out_size, void* d_ws,
                              size_t ws_size, hipStream_t stream) {
  const float* ze = (const float*)d_in[0];
  const float* cb = (const float*)d_in[1];
  float* out = (float*)d_out;

  unsigned short* Cs = (unsigned short*)d_ws;
  float* cnorm = (float*)((char*)d_ws + CNORM_OFF);
  int* qcnt = (int*)((char*)d_ws + QCNT_OFF);
  int* qtok = (int*)((char*)d_ws + QTOK_OFF);
  unsigned long long* kmin = (unsigned long long*)((char*)d_ws + KMIN_OFF);
  float4* partials = (float4*)((char*)d_ws + PART_OFF);

  prep_kernel<<<KCODES / 4, 256, 0, stream>>>(cb, Cs, cnorm, qcnt);
  vq_mfma_kernel<<<dim3(M_TOK / BM, NCHUNK), 256, 0, stream>>>(
      ze, Cs, cnorm, partials);
  merge_kernel<<<M_TOK / 64, 256, 0, stream>>>(
      cb, partials, qcnt, qtok, kmin, out, out + (size_t)M_TOK * DIM);
  rescan_part_kernel<<<4096, 256, 0, stream>>>(ze, cb, cnorm, qcnt, qtok,
                                               kmin);
  rescan_apply_kernel<<<256, 256, 0, stream>>>(cb, qcnt, qtok, kmin, out,
                                               out + (size_t)M_TOK * DIM);
}

// Round 8
// 345.496 us; speedup vs baseline: 1.7477x; 1.7477x over previous
//
#include <hip/hip_runtime.h>

// VQ argmin: 1-pass f16 screen on matrix cores (verified R6 kernel, byte-
// identical) + exact fp32 rescan for tokens with screen gap < MARGIN.
// R8: rescan rewritten for locality — each wave holds 16 code rows in
// REGISTERS (loaded once, coalesced) and streams the flagged tokens past
// them; codebook is read once total instead of per-token.

#define M_TOK  32768
#define DIM    128
#define KCODES 8192
#define BM     64
#define NT     (KCODES / 256)   // 32 n-tiles per block
#define MARGIN 0.10f            // ~8 sigma of screen pair error

typedef _Float16 half8v __attribute__((ext_vector_type(8)));
typedef float float4v __attribute__((ext_vector_type(4)));

union H2U { _Float16 h; unsigned short u; };
__device__ __forceinline__ unsigned short f2h_bits(_Float16 h) {
  H2U c; c.h = h; return c.u;
}

__device__ __forceinline__ void gload_lds16(const void* g, void* l) {
  __builtin_amdgcn_global_load_lds(
      (const __attribute__((address_space(1))) unsigned int*)g,
      (__attribute__((address_space(3))) unsigned int*)l, 16, 0, 0);
}

// ws layout: Cs f16[K][128] (hi only) | cnorm f32[K] | qcnt | qtok | kmin
#define CNORM_OFF  (KCODES * 256)
#define QCNT_OFF   (CNORM_OFF + KCODES * 4)
#define QTOK_OFF   (QCNT_OFF + 64)
#define KMIN_OFF   (QTOK_OFF + M_TOK * 4)

// -------------------------------------------------------------------------
// prep: exact fp32 cnorm + f16-hi codebook rows. Zeroes qcnt.
__global__ __launch_bounds__(256) void prep_kernel(
    const float* __restrict__ cb, unsigned short* __restrict__ Cs,
    float* __restrict__ cnorm, int* __restrict__ qcnt) {
  if (blockIdx.x == 0 && threadIdx.x == 0) *qcnt = 0;
  const int k = blockIdx.x * 4 + (threadIdx.x >> 6);
  const int lane = threadIdx.x & 63;
  const float2 v = ((const float2*)(cb + (size_t)k * DIM))[lane];
  float s = v.x * v.x + v.y * v.y;
  #pragma unroll
  for (int off = 32; off > 0; off >>= 1) s += __shfl_down(s, off);
  if (lane == 0) cnorm[k] = s;
  ushort2 hi;
  hi.x = f2h_bits((_Float16)v.x);
  hi.y = f2h_bits((_Float16)v.y);
  *(ushort2*)(Cs + (size_t)k * 128 + lane * 2) = hi;
}

// -------------------------------------------------------------------------
// Main screen kernel — VERIFIED R6 VERSION, unchanged.
__global__ __launch_bounds__(256, 2) void vq_mfma_kernel(
    const float* __restrict__ ze, const unsigned short* __restrict__ Cs,
    const float* __restrict__ cnorm, const float* __restrict__ cb,
    int* __restrict__ qcnt, int* __restrict__ qtok,
    unsigned long long* __restrict__ kmin,
    float* __restrict__ out_zq, float* __restrict__ out_idx) {
  __shared__ char lds[49152];
  char* const As = lds;            // 16 KB: 64 rows x 256 B, seg-XOR swizzled
  char* const Bs = lds + 16384;    // 32 KB: 4 waves x 8 KB (2 slice bufs)

  const int tid = threadIdx.x;
  const int wn = tid >> 6;
  const int lane = tid & 63;
  const int quad = lane >> 4;
  const int l15 = lane & 15;
  const int m0 = blockIdx.x * BM;

  int loffC[4];
  #pragma unroll
  for (int c = 0; c < 4; ++c) {
    const int r = c * 16 + (lane >> 2);
    const int s = lane & 3;
    const int seg = s ^ ((r >> 1) & 3);
    loffC[c] = (wn * 64 + r) * 256 + seg * 16;
  }
  int boff[4];
  #pragma unroll
  for (int j = 0; j < 4; ++j) {
    const int n = j * 16 + l15;
    boff[j] = n * 64 + ((quad ^ ((n >> 1) & 3)) << 4);
  }
  char* const BsW = Bs + wn * 8192;

  {
    const int r = tid >> 2;
    const int qh = tid & 3;
    const float* zrow = ze + (size_t)(m0 + r) * DIM + qh * 32;
    char* arow = As + r * 256;
    const int rx = r & 7;
    #pragma unroll
    for (int i = 0; i < 8; ++i) {
      const float4 v = *(const float4*)(zrow + i * 4);
      ushort4 hh;
      hh.x = f2h_bits((_Float16)v.x);
      hh.y = f2h_bits((_Float16)v.y);
      hh.z = f2h_bits((_Float16)v.z);
      hh.w = f2h_bits((_Float16)v.w);
      const int c = qh * 32 + i * 4;
      *(ushort4*)(arow + ((((c >> 3) ^ rx) << 4) | ((c & 7) << 1))) = hh;
    }
  }
  __syncthreads();

  half8v ahi[4][4];
  #pragma unroll
  for (int ks = 0; ks < 4; ++ks)
    #pragma unroll
    for (int i = 0; i < 4; ++i) {
      const int m = i * 16 + l15;
      const int kslot = ks * 4 + quad;
      ahi[ks][i] = *(const half8v*)(As + m * 256 + ((kslot ^ (m & 7)) << 4));
    }

  float bestv[16], secv[16], idxv[16];
  #pragma unroll
  for (int s = 0; s < 16; ++s) {
    bestv[s] = 3.4e38f; secv[s] = 3.4e38f; idxv[s] = 0.f;
  }

  for (int nt = 0; nt < NT; ++nt) {
    const char* const tile = (const char*)Cs + (size_t)nt * 65536;
    float cnv[4];
    #pragma unroll
    for (int j = 0; j < 4; ++j)
      cnv[j] = cnorm[nt * 256 + wn * 64 + j * 16 + l15];

    float4v acc[4][4];
    #pragma unroll
    for (int i = 0; i < 4; ++i)
      #pragma unroll
      for (int j = 0; j < 4; ++j) acc[i][j] = (float4v)0.0f;

    #pragma unroll
    for (int t = 0; t < 2; ++t) {
      __syncthreads();
      #pragma unroll
      for (int p = 0; p < 2; ++p)
        #pragma unroll
        for (int c = 0; c < 4; ++c)
          gload_lds16(tile + (t * 2 + p) * 64 + loffC[c],
                      BsW + p * 4096 + c * 1024);
      __syncthreads();

      #pragma unroll
      for (int p = 0; p < 2; ++p) {
        const int kk = t * 2 + p;
        half8v bf[4];
        #pragma unroll
        for (int j = 0; j < 4; ++j)
          bf[j] = *(const half8v*)(BsW + p * 4096 + boff[j]);
        #pragma unroll
        for (int i = 0; i < 4; ++i)
          #pragma unroll
          for (int j = 0; j < 4; ++j)
            acc[i][j] = __builtin_amdgcn_mfma_f32_16x16x32_f16(
                ahi[kk][i], bf[j], acc[i][j], 0, 0, 0);
      }
    }

    #pragma unroll
    for (int j = 0; j < 4; ++j) {
      const float nidx = (float)(nt * 256 + wn * 64 + j * 16 + l15);
      const float cn = cnv[j];
      #pragma unroll
      for (int i = 0; i < 4; ++i)
        #pragma unroll
        for (int rg = 0; rg < 4; ++rg) {
          const float sc = fmaf(-2.0f, acc[i][j][rg], cn);
          const int slot = i * 4 + rg;
          const bool bt = sc < bestv[slot];
          secv[slot] = bt ? bestv[slot] : fminf(secv[slot], sc);
          idxv[slot] = bt ? nidx : idxv[slot];
          bestv[slot] = bt ? sc : bestv[slot];
        }
    }
  }

  #pragma unroll
  for (int slot = 0; slot < 16; ++slot) {
    float b = bestv[slot], sec = secv[slot], ix = idxv[slot];
    #pragma unroll
    for (int mk = 1; mk <= 8; mk <<= 1) {
      const float ob = __shfl_xor(b, mk);
      const float os = __shfl_xor(sec, mk);
      const float oi = __shfl_xor(ix, mk);
      const bool take = (ob < b) || (ob == b && oi < ix);
      const float loser = take ? b : ob;
      b = take ? ob : b;
      ix = take ? oi : ix;
      sec = fminf(fminf(sec, os), loser);
    }
    bestv[slot] = b; secv[slot] = sec; idxv[slot] = ix;
  }

  __syncthreads();
  float* const redB = (float*)lds;
  float* const redS = redB + 256;
  float* const redI = redB + 512;
  float* const lidxs = redB + 768;
  if (l15 == 0) {
    #pragma unroll
    for (int slot = 0; slot < 16; ++slot) {
      const int row = (slot >> 2) * 16 + quad * 4 + (slot & 3);
      redB[wn * 64 + row] = bestv[slot];
      redS[wn * 64 + row] = secv[slot];
      redI[wn * 64 + row] = idxv[slot];
    }
  }
  __syncthreads();
  if (tid < 64) {
    float b = redB[tid], sec = redS[tid], ix = redI[tid];
    #pragma unroll
    for (int w = 1; w < 4; ++w) {
      const float ob = redB[w * 64 + tid];
      const float os = redS[w * 64 + tid];
      const float oi = redI[w * 64 + tid];
      const bool take = (ob < b) || (ob == b && oi < ix);
      const float loser = take ? b : ob;
      b = take ? ob : b;
      ix = take ? oi : ix;
      sec = fminf(fminf(sec, os), loser);
    }
    out_idx[m0 + tid] = ix;
    lidxs[tid] = ix;
    if (sec - b < MARGIN) {
      kmin[m0 + tid] = ~0ull;
      const int p = atomicAdd(qcnt, 1);
      qtok[p] = m0 + tid;
    }
  }
  __syncthreads();

  const int tl = tid >> 2, qp = tid & 3;
  const int code = (int)lidxs[tl];
  const float4* src = (const float4*)(cb + (size_t)code * DIM);
  float4* dst = (float4*)(out_zq + (size_t)(m0 + tl) * DIM);
  #pragma unroll
  for (int p = 0; p < 8; ++p) dst[qp + p * 4] = src[qp + p * 4];
}

// -------------------------------------------------------------------------
// R8 rescan: 512 blocks = 128 code-chunks (64 codes) x 4 token-splits.
// Wave wn owns 16 codes, held in REGISTERS: lane (cs=lane>>4, dl=lane&15)
// holds dims [dl*8, dl*8+8) of codes {chunk*64+wn*16+it*4+cs}. Per flagged
// token: 2 x-row loads, 8 FMA + xor-1/2/4/8 dot-reduce per code group,
// xor-16/32 argmin merge, one atomicMin per wave. Exact fp32 throughout.
__global__ __launch_bounds__(256) void rescan_part_kernel(
    const float* __restrict__ ze, const float* __restrict__ cb,
    const float* __restrict__ cnorm, const int* __restrict__ qcnt,
    const int* __restrict__ qtok, unsigned long long* __restrict__ kmin) {
  const int tid = threadIdx.x;
  const int wn = tid >> 6;
  const int lane = tid & 63;
  const int cs = lane >> 4;     // code sub-slot 0..3
  const int dl = lane & 15;     // dim lane: dims dl*8 .. dl*8+8
  const int chunk = blockIdx.x & 127;
  const int split = blockIdx.x >> 7;    // 0..3
  const int n = *qcnt;
  if (n == 0) return;

  // Load this lane's code-row segments into registers (once).
  float4 ca[4], cbv[4];
  float cn[4];
  int codes[4];
  #pragma unroll
  for (int it = 0; it < 4; ++it) {
    const int c = chunk * 64 + wn * 16 + it * 4 + cs;
    codes[it] = c;
    cn[it] = cnorm[c];
    const float* crow = cb + (size_t)c * DIM + dl * 8;
    ca[it] = *(const float4*)crow;
    cbv[it] = *(const float4*)(crow + 4);
  }

  for (int qi = split; qi < n; qi += 4) {
    const int token = qtok[qi];
    const float* xrow = ze + (size_t)token * DIM + dl * 8;
    const float4 xa = *(const float4*)xrow;
    const float4 xb = *(const float4*)(xrow + 4);

    float b = 3.4e38f;
    int bi = 0;
    #pragma unroll
    for (int it = 0; it < 4; ++it) {
      float p = xa.x * ca[it].x;
      p = fmaf(xa.y, ca[it].y, p);
      p = fmaf(xa.z, ca[it].z, p);
      p = fmaf(xa.w, ca[it].w, p);
      p = fmaf(xb.x, cbv[it].x, p);
      p = fmaf(xb.y, cbv[it].y, p);
      p = fmaf(xb.z, cbv[it].z, p);
      p = fmaf(xb.w, cbv[it].w, p);
      // dot-reduce over dim lanes (bits 0..3)
      #pragma unroll
      for (int mk = 1; mk <= 8; mk <<= 1) p += __shfl_xor(p, mk);
      const float sc = fmaf(-2.f, p, cn[it]);
      if (sc < b || (sc == b && codes[it] < bi)) { b = sc; bi = codes[it]; }
    }
    // argmin merge across code sub-slots (lane bits 4..5)
    #pragma unroll
    for (int mk = 16; mk <= 32; mk <<= 1) {
      const float ob = __shfl_xor(b, mk);
      const int oi = __shfl_xor(bi, mk);
      if (ob < b || (ob == b && oi < bi)) { b = ob; bi = oi; }
    }
    if (lane == 0) {
      union { float f; unsigned int u; } c; c.f = b;
      const unsigned int m = (c.u >> 31) ? ~c.u : (c.u | 0x80000000u);
      const unsigned long long key =
          ((unsigned long long)m << 32) | (unsigned int)bi;
      atomicMin(&kmin[token], key);
    }
  }
}

// -------------------------------------------------------------------------
// Apply rescan results: decode keys, rewrite idx + z_q rows.
__global__ __launch_bounds__(256) void rescan_apply_kernel(
    const float* __restrict__ cb, const int* __restrict__ qcnt,
    const int* __restrict__ qtok, const unsigned long long* __restrict__ kmin,
    float* __restrict__ out_zq, float* __restrict__ out_idx) {
  const int tid = threadIdx.x;
  const int n = *qcnt;
  for (int qi = blockIdx.x; qi < n; qi += gridDim.x) {
    const int token = qtok[qi];
    const int code = (int)(unsigned int)(kmin[token] & 0xFFFFFFFFull);
    if (tid == 0) out_idx[token] = (float)code;
    if (tid < 32)
      ((float4*)(out_zq + (size_t)token * DIM))[tid] =
          ((const float4*)(cb + (size_t)code * DIM))[tid];
  }
}

// -------------------------------------------------------------------------
extern "C" void kernel_launch(void* const* d_in, const int* in_sizes, int n_in,
                              void* d_out, int out_size, void* d_ws,
                              size_t ws_size, hipStream_t stream) {
  const float* ze = (const float*)d_in[0];
  const float* cb = (const float*)d_in[1];
  float* out = (float*)d_out;

  unsigned short* Cs = (unsigned short*)d_ws;
  float* cnorm = (float*)((char*)d_ws + CNORM_OFF);
  int* qcnt = (int*)((char*)d_ws + QCNT_OFF);
  int* qtok = (int*)((char*)d_ws + QTOK_OFF);
  unsigned long long* kmin = (unsigned long long*)((char*)d_ws + KMIN_OFF);

  prep_kernel<<<KCODES / 4, 256, 0, stream>>>(cb, Cs, cnorm, qcnt);
  vq_mfma_kernel<<<M_TOK / BM, 256, 0, stream>>>(
      ze, Cs, cnorm, cb, qcnt, qtok, kmin, out, out + (size_t)M_TOK * DIM);
  rescan_part_kernel<<<512, 256, 0, stream>>>(ze, cb, cnorm, qcnt, qtok,
                                              kmin);
  rescan_apply_kernel<<<256, 256, 0, stream>>>(cb, qcnt, qtok, kmin, out,
                                               out + (size_t)M_TOK * DIM);
}

// Round 9
// 275.327 us; speedup vs baseline: 2.1931x; 1.2549x over previous
//
#include <hip/hip_runtime.h>

// VQ argmin: 2-pass f16 screen on matrix cores (xh.ch + xl.ch — x-side
// exact, c-side f16 error only, sigma_pair ~4.5e-3) + exact fp32 parallel
// rescan for tokens with screen gap < MARGIN (~0.4% of tokens).
// The xl pass reuses the SAME staged B slices (no extra staging/barriers).
// K-loop staging, swizzles, fold, rescan: all R2/R4/R5/R6-verified parts.

#define M_TOK  32768
#define DIM    128
#define KCODES 8192
#define BM     64
#define NT     (KCODES / 256)   // 32 n-tiles per block
#define MARGIN 0.05f            // ~11 sigma of 2-pass screen pair error

typedef _Float16 half8v __attribute__((ext_vector_type(8)));
typedef float float4v __attribute__((ext_vector_type(4)));

union H2U { _Float16 h; unsigned short u; };
__device__ __forceinline__ unsigned short f2h_bits(_Float16 h) {
  H2U c; c.h = h; return c.u;
}

__device__ __forceinline__ void gload_lds16(const void* g, void* l) {
  __builtin_amdgcn_global_load_lds(
      (const __attribute__((address_space(1))) unsigned int*)g,
      (__attribute__((address_space(3))) unsigned int*)l, 16, 0, 0);
}

// ws layout: Cs f16[K][128] (hi only) | cnorm f32[K] | qcnt | qtok | kmin
#define CNORM_OFF  (KCODES * 256)
#define QCNT_OFF   (CNORM_OFF + KCODES * 4)
#define QTOK_OFF   (QCNT_OFF + 64)
#define KMIN_OFF   (QTOK_OFF + M_TOK * 4)

// -------------------------------------------------------------------------
// prep: exact fp32 cnorm + f16-hi codebook rows. Zeroes qcnt.
__global__ __launch_bounds__(256) void prep_kernel(
    const float* __restrict__ cb, unsigned short* __restrict__ Cs,
    float* __restrict__ cnorm, int* __restrict__ qcnt) {
  if (blockIdx.x == 0 && threadIdx.x == 0) *qcnt = 0;
  const int k = blockIdx.x * 4 + (threadIdx.x >> 6);
  const int lane = threadIdx.x & 63;
  const float2 v = ((const float2*)(cb + (size_t)k * DIM))[lane];
  float s = v.x * v.x + v.y * v.y;
  #pragma unroll
  for (int off = 32; off > 0; off >>= 1) s += __shfl_down(s, off);
  if (lane == 0) cnorm[k] = s;
  ushort2 hi;
  hi.x = f2h_bits((_Float16)v.x);
  hi.y = f2h_bits((_Float16)v.y);
  *(ushort2*)(Cs + (size_t)k * 128 + lane * 2) = hi;
}

// -------------------------------------------------------------------------
// Main screen kernel. As holds xh|xl (R4-verified 512 B-row layout); B
// slices staged once, consumed by BOTH ahi and alo MFMA passes.
__global__ __launch_bounds__(256, 2) void vq_mfma_kernel(
    const float* __restrict__ ze, const unsigned short* __restrict__ Cs,
    const float* __restrict__ cnorm, const float* __restrict__ cb,
    int* __restrict__ qcnt, int* __restrict__ qtok,
    unsigned long long* __restrict__ kmin,
    float* __restrict__ out_zq, float* __restrict__ out_idx) {
  __shared__ char lds[65536];
  char* const As = lds;            // 32 KB: 64 rows x 512 B (xh|xl), swizzled
  char* const Bs = lds + 32768;    // 32 KB: 4 waves x 8 KB (2 slice bufs)

  const int tid = threadIdx.x;
  const int wn = tid >> 6;
  const int lane = tid & 63;
  const int quad = lane >> 4;
  const int l15 = lane & 15;
  const int m0 = blockIdx.x * BM;

  int loffC[4];
  #pragma unroll
  for (int c = 0; c < 4; ++c) {
    const int r = c * 16 + (lane >> 2);
    const int s = lane & 3;
    const int seg = s ^ ((r >> 1) & 3);
    loffC[c] = (wn * 64 + r) * 256 + seg * 16;
  }
  int boff[4];
  #pragma unroll
  for (int j = 0; j < 4; ++j) {
    const int n = j * 16 + l15;
    boff[j] = n * 64 + ((quad ^ ((n >> 1) & 3)) << 4);
  }
  char* const BsW = Bs + wn * 8192;

  // ---- stage As: fp32 -> (xh|xl) f16, seg = (c>>3) ^ (r&7) (R4-verified) --
  {
    const int r = tid >> 2;
    const int qh = tid & 3;
    const float* zrow = ze + (size_t)(m0 + r) * DIM + qh * 32;
    char* arow = As + r * 512;
    const int rx = r & 7;
    #pragma unroll
    for (int i = 0; i < 8; ++i) {
      const float4 v = *(const float4*)(zrow + i * 4);
      const _Float16 h0 = (_Float16)v.x, h1 = (_Float16)v.y,
                     h2 = (_Float16)v.z, h3 = (_Float16)v.w;
      ushort4 hh, ll;
      hh.x = f2h_bits(h0); hh.y = f2h_bits(h1);
      hh.z = f2h_bits(h2); hh.w = f2h_bits(h3);
      ll.x = f2h_bits((_Float16)(v.x - (float)h0));
      ll.y = f2h_bits((_Float16)(v.y - (float)h1));
      ll.z = f2h_bits((_Float16)(v.z - (float)h2));
      ll.w = f2h_bits((_Float16)(v.w - (float)h3));
      const int c = qh * 32 + i * 4;
      *(ushort4*)(arow + ((((c >> 3) ^ rx) << 4) | ((c & 7) << 1))) = hh;
      const int c2 = c + 128;
      *(ushort4*)(arow + ((((c2 >> 3) ^ rx) << 4) | ((c2 & 7) << 1))) = ll;
    }
  }
  __syncthreads();

  // Preload A-hi fragments (registers, reused for all n-tiles).
  half8v ahi[4][4];
  #pragma unroll
  for (int ks = 0; ks < 4; ++ks)
    #pragma unroll
    for (int i = 0; i < 4; ++i) {
      const int m = i * 16 + l15;
      const int kslot = ks * 4 + quad;
      ahi[ks][i] = *(const half8v*)(As + m * 512 + ((kslot ^ (m & 7)) << 4));
    }

  float bestv[16], secv[16], idxv[16];
  #pragma unroll
  for (int s = 0; s < 16; ++s) {
    bestv[s] = 3.4e38f; secv[s] = 3.4e38f; idxv[s] = 0.f;
  }

  for (int nt = 0; nt < NT; ++nt) {
    const char* const tile = (const char*)Cs + (size_t)nt * 65536;
    float cnv[4];
    #pragma unroll
    for (int j = 0; j < 4; ++j)
      cnv[j] = cnorm[nt * 256 + wn * 64 + j * 16 + l15];

    float4v acc[4][4];
    #pragma unroll
    for (int i = 0; i < 4; ++i)
      #pragma unroll
      for (int j = 0; j < 4; ++j) acc[i][j] = (float4v)0.0f;

    #pragma unroll
    for (int t = 0; t < 2; ++t) {
      __syncthreads();
      #pragma unroll
      for (int p = 0; p < 2; ++p)
        #pragma unroll
        for (int c = 0; c < 4; ++c)
          gload_lds16(tile + (t * 2 + p) * 64 + loffC[c],
                      BsW + p * 4096 + c * 1024);
      __syncthreads();

      #pragma unroll
      for (int p = 0; p < 2; ++p) {
        const int kk = t * 2 + p;
        half8v bf[4];
        #pragma unroll
        for (int j = 0; j < 4; ++j)
          bf[j] = *(const half8v*)(BsW + p * 4096 + boff[j]);
        // Pass 1: xh.ch (registers)
        #pragma unroll
        for (int i = 0; i < 4; ++i)
          #pragma unroll
          for (int j = 0; j < 4; ++j)
            acc[i][j] = __builtin_amdgcn_mfma_f32_16x16x32_f16(
                ahi[kk][i], bf[j], acc[i][j], 0, 0, 0);
        // Pass 2: xl.ch (alo from LDS, R4-verified path) — SAME B slice.
        half8v alo[4];
        #pragma unroll
        for (int i = 0; i < 4; ++i) {
          const int m = i * 16 + l15;
          const int kslot = 16 + kk * 4 + quad;
          alo[i] = *(const half8v*)(As + m * 512 + ((kslot ^ (m & 7)) << 4));
        }
        #pragma unroll
        for (int i = 0; i < 4; ++i)
          #pragma unroll
          for (int j = 0; j < 4; ++j)
            acc[i][j] = __builtin_amdgcn_mfma_f32_16x16x32_f16(
                alo[i], bf[j], acc[i][j], 0, 0, 0);
      }
    }

    // Fold screen scores. Ascending n, strict < -> lowest index on ties.
    #pragma unroll
    for (int j = 0; j < 4; ++j) {
      const float nidx = (float)(nt * 256 + wn * 64 + j * 16 + l15);
      const float cn = cnv[j];
      #pragma unroll
      for (int i = 0; i < 4; ++i)
        #pragma unroll
        for (int rg = 0; rg < 4; ++rg) {
          const float sc = fmaf(-2.0f, acc[i][j][rg], cn);
          const int slot = i * 4 + rg;
          const bool bt = sc < bestv[slot];
          secv[slot] = bt ? bestv[slot] : fminf(secv[slot], sc);
          idxv[slot] = bt ? nidx : idxv[slot];
          bestv[slot] = bt ? sc : bestv[slot];
        }
    }
  }

  // Cross-lane reduce (16 lanes per token row, tie -> lowest index).
  #pragma unroll
  for (int slot = 0; slot < 16; ++slot) {
    float b = bestv[slot], sec = secv[slot], ix = idxv[slot];
    #pragma unroll
    for (int mk = 1; mk <= 8; mk <<= 1) {
      const float ob = __shfl_xor(b, mk);
      const float os = __shfl_xor(sec, mk);
      const float oi = __shfl_xor(ix, mk);
      const bool take = (ob < b) || (ob == b && oi < ix);
      const float loser = take ? b : ob;
      b = take ? ob : b;
      ix = take ? oi : ix;
      sec = fminf(fminf(sec, os), loser);
    }
    bestv[slot] = b; secv[slot] = sec; idxv[slot] = ix;
  }

  // Cross-wave merge via LDS (As region reused after barrier).
  __syncthreads();
  float* const redB = (float*)lds;
  float* const redS = redB + 256;
  float* const redI = redB + 512;
  float* const lidxs = redB + 768;
  if (l15 == 0) {
    #pragma unroll
    for (int slot = 0; slot < 16; ++slot) {
      const int row = (slot >> 2) * 16 + quad * 4 + (slot & 3);
      redB[wn * 64 + row] = bestv[slot];
      redS[wn * 64 + row] = secv[slot];
      redI[wn * 64 + row] = idxv[slot];
    }
  }
  __syncthreads();
  if (tid < 64) {
    float b = redB[tid], sec = redS[tid], ix = redI[tid];
    #pragma unroll
    for (int w = 1; w < 4; ++w) {
      const float ob = redB[w * 64 + tid];
      const float os = redS[w * 64 + tid];
      const float oi = redI[w * 64 + tid];
      const bool take = (ob < b) || (ob == b && oi < ix);
      const float loser = take ? b : ob;
      b = take ? ob : b;
      ix = take ? oi : ix;
      sec = fminf(fminf(sec, os), loser);
    }
    out_idx[m0 + tid] = ix;
    lidxs[tid] = ix;
    if (sec - b < MARGIN) {  // ambiguous under c-side f16 error -> rescan
      kmin[m0 + tid] = ~0ull;
      const int p = atomicAdd(qcnt, 1);
      qtok[p] = m0 + tid;
    }
  }
  __syncthreads();

  const int tl = tid >> 2, qp = tid & 3;
  const int code = (int)lidxs[tl];
  const float4* src = (const float4*)(cb + (size_t)code * DIM);
  float4* dst = (float4*)(out_zq + (size_t)(m0 + tl) * DIM);
  #pragma unroll
  for (int p = 0; p < 8; ++p) dst[qp + p * 4] = src[qp + p * 4];
}

// -------------------------------------------------------------------------
// Parallel exact rescan (verified R5/R6): block b = (token slot b>>5,
// code chunk b&31); 256 threads score one code each; atomicMin merge.
__global__ __launch_bounds__(256) void rescan_part_kernel(
    const float* __restrict__ ze, const float* __restrict__ cb,
    const float* __restrict__ cnorm, const int* __restrict__ qcnt,
    const int* __restrict__ qtok, unsigned long long* __restrict__ kmin) {
  __shared__ float xsh[DIM];
  __shared__ float rs[256];
  __shared__ int ri[256];
  const int tid = threadIdx.x;
  const int chunk = blockIdx.x & 31;
  const int n = *qcnt;
  for (int qi = blockIdx.x >> 5; qi < n; qi += (gridDim.x >> 5)) {
    const int token = qtok[qi];
    __syncthreads();
    if (tid < 32)
      ((float4*)xsh)[tid] = ((const float4*)(ze + (size_t)token * DIM))[tid];
    __syncthreads();
    const int code = chunk * 256 + tid;
    const float* crow = cb + (size_t)code * DIM;
    float dot = 0.f;
    #pragma unroll
    for (int d = 0; d < DIM; ++d) dot = fmaf(xsh[d], crow[d], dot);
    rs[tid] = fmaf(-2.f, dot, cnorm[code]);
    ri[tid] = code;
    __syncthreads();
    #pragma unroll
    for (int off = 128; off > 0; off >>= 1) {
      if (tid < off) {
        const float so = rs[tid + off];
        const int io = ri[tid + off];
        if (so < rs[tid] || (so == rs[tid] && io < ri[tid])) {
          rs[tid] = so; ri[tid] = io;
        }
      }
      __syncthreads();
    }
    if (tid == 0) {
      union { float f; unsigned int u; } c; c.f = rs[0];
      const unsigned int m = (c.u >> 31) ? ~c.u : (c.u | 0x80000000u);
      const unsigned long long key =
          ((unsigned long long)m << 32) | (unsigned int)ri[0];
      atomicMin(&kmin[token], key);
    }
    __syncthreads();
  }
}

// -------------------------------------------------------------------------
// Apply rescan results: decode keys, rewrite idx + z_q rows.
__global__ __launch_bounds__(256) void rescan_apply_kernel(
    const float* __restrict__ cb, const int* __restrict__ qcnt,
    const int* __restrict__ qtok, const unsigned long long* __restrict__ kmin,
    float* __restrict__ out_zq, float* __restrict__ out_idx) {
  const int tid = threadIdx.x;
  const int n = *qcnt;
  for (int qi = blockIdx.x; qi < n; qi += gridDim.x) {
    const int token = qtok[qi];
    const int code = (int)(unsigned int)(kmin[token] & 0xFFFFFFFFull);
    if (tid == 0) out_idx[token] = (float)code;
    if (tid < 32)
      ((float4*)(out_zq + (size_t)token * DIM))[tid] =
          ((const float4*)(cb + (size_t)code * DIM))[tid];
  }
}

// -------------------------------------------------------------------------
extern "C" void kernel_launch(void* const* d_in, const int* in_sizes, int n_in,
                              void* d_out, int out_size, void* d_ws,
                              size_t ws_size, hipStream_t stream) {
  const float* ze = (const float*)d_in[0];
  const float* cb = (const float*)d_in[1];
  float* out = (float*)d_out;

  unsigned short* Cs = (unsigned short*)d_ws;
  float* cnorm = (float*)((char*)d_ws + CNORM_OFF);
  int* qcnt = (int*)((char*)d_ws + QCNT_OFF);
  int* qtok = (int*)((char*)d_ws + QTOK_OFF);
  unsigned long long* kmin = (unsigned long long*)((char*)d_ws + KMIN_OFF);

  prep_kernel<<<KCODES / 4, 256, 0, stream>>>(cb, Cs, cnorm, qcnt);
  vq_mfma_kernel<<<M_TOK / BM, 256, 0, stream>>>(
      ze, Cs, cnorm, cb, qcnt, qtok, kmin, out, out + (size_t)M_TOK * DIM);
  rescan_part_kernel<<<4096, 256, 0, stream>>>(ze, cb, cnorm, qcnt, qtok,
                                               kmin);
  rescan_apply_kernel<<<256, 256, 0, stream>>>(cb, qcnt, qtok, kmin, out,
                                               out + (size_t)M_TOK * DIM);
}